// Round 7
// baseline (1182.658 us; speedup 1.0000x reference)
//
#include <hip/hip_runtime.h>

#define NN 50000
#define NE 1600000
#define NR 8
#define ND 128
#define NL 3
#define NS 4       // feature slices
#define RN (NR * NN)
#define SCAN_BLK 1024
#define NB ((RN + SCAN_BLK - 1) / SCAN_BLK)  // 391
#define LN_EPS 1e-5f
#define TP 20      // dwords per LDS tile row (16 + 4 pad, 16B-aligned rows)
#define PADF 132   // f32 elems per epilogue scratch row

typedef __attribute__((ext_vector_type(8))) short short8;
typedef __attribute__((ext_vector_type(4))) float float4v;

__device__ __forceinline__ float bflo(unsigned u) { return __uint_as_float(u << 16); }
__device__ __forceinline__ float bfhi(unsigned u) { return __uint_as_float(u & 0xFFFF0000u); }
__device__ __forceinline__ unsigned f2bf(float f) {
    unsigned u = __float_as_uint(f);
    return (u + 0x7FFFu + ((u >> 16) & 1u)) >> 16;   // RNE
}
__device__ __forceinline__ unsigned pack2(float lo, float hi) {
    return f2bf(lo) | (f2bf(hi) << 16);
}

// h (slice-major bf16x2): h[((p*NN)+n)*16 + w] holds cols 32p+2w, 32p+2w+1
__global__ __launch_bounds__(256) void k_gather(const int* __restrict__ x,
                                                const float* __restrict__ emb,
                                                unsigned* __restrict__ h) {
    int i = blockIdx.x * 256 + threadIdx.x;       // over NN*64 dwords
    if (i >= NN * 64) return;
    int n = i >> 6, dw = i & 63;
    int p = dw >> 4, w = dw & 15;
    float2 v = *(const float2*)&emb[(size_t)x[n] * ND + 2 * dw];
    h[((size_t)p * NN + n) * 16 + w] = pack2(v.x, v.y);
}

// weights -> bf16 B-fragment layout: wb[m][((kk*8+ft)*64+lane)*8+j] = W_m[kk*32+(lane>>4)*8+j][ft*16+(lane&15)]
// (kk doubles as the feature-slice index p in k_layer)
__global__ __launch_bounds__(256) void k_wprep(const float* __restrict__ w_rel,
                                               const float* __restrict__ w_root,
                                               unsigned short* __restrict__ wb) {
    int i = blockIdx.x * 256 + threadIdx.x;
    if (i >= 27 * 16384) return;
    int m = i >> 14;
    int idx = i & 16383;
    int j = idx & 7;
    int lane = (idx >> 3) & 63;
    int ft = (idx >> 9) & 7;
    int kk = idx >> 12;
    int row = kk * 32 + (lane >> 4) * 8 + j;
    int col = ft * 16 + (lane & 15);
    const float* W = (m < 24) ? (w_rel + (size_t)m * 16384)
                              : (w_root + (size_t)(m - 24) * 16384);
    wb[i] = (unsigned short)f2bf(W[row * ND + col]);
}

__global__ __launch_bounds__(256) void k_count(const int* __restrict__ dst,
                                               const int* __restrict__ et,
                                               int* __restrict__ cnt) {
    int e = blockIdx.x * 256 + threadIdx.x;
    if (e >= NE) return;
    atomicAdd(&cnt[et[e] * NN + dst[e]], 1);
}

__global__ __launch_bounds__(256) void k_inv(const int* __restrict__ cnt,
                                             float* __restrict__ inv) {
    int i = blockIdx.x * 256 + threadIdx.x;
    if (i >= RN) return;
    int c = cnt[i];
    inv[i] = 1.0f / (float)(c > 1 ? c : 1);
}

__global__ __launch_bounds__(256) void k_scan1(const int* __restrict__ cnt,
                                               int* __restrict__ rowstart,
                                               int* __restrict__ bsum) {
    __shared__ int tmp[256];
    int t = threadIdx.x;
    int base = blockIdx.x * SCAN_BLK + t * 4;
    int v[4];
#pragma unroll
    for (int i = 0; i < 4; i++) v[i] = (base + i < RN) ? cnt[base + i] : 0;
    int local = v[0] + v[1] + v[2] + v[3];
    tmp[t] = local;
    __syncthreads();
    for (int off = 1; off < 256; off <<= 1) {
        int x = (t >= off) ? tmp[t - off] : 0;
        __syncthreads();
        tmp[t] += x;
        __syncthreads();
    }
    int run = tmp[t] - local;
    if (t == 255) bsum[blockIdx.x] = tmp[t];
#pragma unroll
    for (int i = 0; i < 4; i++) {
        if (base + i < RN) rowstart[base + i] = run;
        run += v[i];
    }
}

__global__ __launch_bounds__(256) void k_scan2(const int* __restrict__ bsum,
                                               int* __restrict__ boff) {
    __shared__ int tmp[256];
    int t = threadIdx.x;
    int v0 = (2 * t < NB) ? bsum[2 * t] : 0;
    int v1 = (2 * t + 1 < NB) ? bsum[2 * t + 1] : 0;
    int local = v0 + v1;
    tmp[t] = local;
    __syncthreads();
    for (int off = 1; off < 256; off <<= 1) {
        int x = (t >= off) ? tmp[t - off] : 0;
        __syncthreads();
        tmp[t] += x;
        __syncthreads();
    }
    int excl = tmp[t] - local;
    if (2 * t < NB) boff[2 * t] = excl;
    if (2 * t + 1 < NB) boff[2 * t + 1] = excl + v0;
}

__global__ __launch_bounds__(256) void k_scan3(int* __restrict__ rowstart,
                                               const int* __restrict__ boff) {
    int i = blockIdx.x * 256 + threadIdx.x;
    if (i < RN) rowstart[i] += boff[i >> 10];
    if (i == 0) rowstart[RN] = NE;
}

__global__ __launch_bounds__(256) void k_fill(const int* __restrict__ src,
                                              const int* __restrict__ dst,
                                              const int* __restrict__ et,
                                              const int* __restrict__ rowstart,
                                              int* __restrict__ cnt,
                                              int* __restrict__ adj) {
    int e = blockIdx.x * 256 + threadIdx.x;
    if (e >= NE) return;
    int seg = et[e] * NN + dst[e];
    int c = atomicSub(&cnt[seg], 1);
    adj[rowstart[seg] + c - 1] = src[e];
}

// Fused RGCN layer, feature-sliced for L2 locality.
// Block = 64 nodes, 8 waves (512 threads). Outer loop: 4 feature slices (3.2 MB
// each -> XCD-L2-resident). Per (slice, relation): 8-lane groups gather 64-byte
// row slices (8 chains/wave, 64 rows in one batch), then waves 0-3 run the
// K=32 MFMA block kk=p, accumulating across slices and relations.
__global__ __launch_bounds__(512) void k_layer(const unsigned* __restrict__ hsl,
                                               const int* __restrict__ adj,
                                               const int* __restrict__ rowstart,
                                               const float* __restrict__ inv,
                                               const unsigned short* __restrict__ wrel,
                                               const unsigned short* __restrict__ wroot,
                                               const float* __restrict__ bias,
                                               const float* __restrict__ gamma,
                                               const float* __restrict__ beta,
                                               float* __restrict__ out_f,
                                               unsigned* __restrict__ out_h,
                                               int add_res, int last) {
    __shared__ float SLF[64 * PADF];                 // 33792 B fp32 epilogue scratch
    unsigned* SLB32 = (unsigned*)SLF;                // aliased bf16 tile [64][TP] dwords

    int tid = threadIdx.x;
    int wave = tid >> 6, lane = tid & 63;
    int quad = lane >> 4, l15 = lane & 15;
    int gi = lane >> 3, li = lane & 7;               // 8-lane gather groups
    int n0 = blockIdx.x * 64;

    float4v acc[8];
#pragma unroll
    for (int i = 0; i < 8; i++) acc[i] = (float4v){0.f, 0.f, 0.f, 0.f};

    for (int p = 0; p < NS; p++) {
        const unsigned* hp = hsl + (size_t)p * NN * 16;
        for (int r = 0; r < NR; r++) {
            // gather+mean: group owns a row; lane li covers dwords 2li,2li+1 of
            // the 16-dword slice row. 64 rows in one batch across 8 waves.
            {
                int row = wave * 8 + gi;
                int g = n0 + row;
                float a0 = 0.f, a1 = 0.f, a2 = 0.f, a3 = 0.f;
                if (g < NN) {
                    int seg = r * NN + g;
                    int st = rowstart[seg], en = rowstart[seg + 1];
                    st = st < 0 ? 0 : st;
                    en = en > NE ? NE : en;
                    float c0 = 0.f, c1 = 0.f, c2 = 0.f, c3 = 0.f;
                    int q = st;
                    for (; q + 1 < en; q += 2) {
                        unsigned s0 = (unsigned)adj[q], s1 = (unsigned)adj[q + 1];
                        s0 = s0 < NN ? s0 : NN - 1;
                        s1 = s1 < NN ? s1 : NN - 1;
                        uint2 u0 = *(const uint2*)&hp[(size_t)s0 * 16 + li * 2];
                        uint2 u1 = *(const uint2*)&hp[(size_t)s1 * 16 + li * 2];
                        a0 += bflo(u0.x); a1 += bfhi(u0.x);
                        a2 += bflo(u0.y); a3 += bfhi(u0.y);
                        c0 += bflo(u1.x); c1 += bfhi(u1.x);
                        c2 += bflo(u1.y); c3 += bfhi(u1.y);
                    }
                    if (q < en) {
                        unsigned s0 = (unsigned)adj[q];
                        s0 = s0 < NN ? s0 : NN - 1;
                        uint2 u0 = *(const uint2*)&hp[(size_t)s0 * 16 + li * 2];
                        a0 += bflo(u0.x); a1 += bfhi(u0.x);
                        a2 += bflo(u0.y); a3 += bfhi(u0.y);
                    }
                    float sc = inv[seg];
                    a0 = (a0 + c0) * sc; a1 = (a1 + c1) * sc;
                    a2 = (a2 + c2) * sc; a3 = (a3 + c3) * sc;
                }
                uint2 w;
                w.x = pack2(a0, a1);
                w.y = pack2(a2, a3);
                *(uint2*)&SLB32[row * TP + li * 2] = w;
            }
            __syncthreads();
            if (wave < 4) {
                const unsigned short* WB = wrel + r * 16384;
                short8 af = *(const short8*)&SLB32[(wave * 16 + l15) * TP + quad * 4];
#pragma unroll
                for (int ft = 0; ft < 8; ft++) {
                    short8 bf = *(const short8*)&WB[((p * 8 + ft) * 64 + lane) * 8];
                    acc[ft] = __builtin_amdgcn_mfma_f32_16x16x32_bf16(af, bf, acc[ft], 0, 0, 0);
                }
            }
            __syncthreads();
        }

        // root transform for this slice: stage h slice tile (coalesced), MFMA kk=p
#pragma unroll
        for (int i = 0; i < 2; i++) {
            int idx = tid + i * 512;                 // 1024 dwords
            int row = idx >> 4, dw = idx & 15;
            int g = n0 + row;
            SLB32[row * TP + dw] = (g < NN) ? hp[(size_t)g * 16 + dw] : 0u;
        }
        __syncthreads();
        if (wave < 4) {
            short8 af = *(const short8*)&SLB32[(wave * 16 + l15) * TP + quad * 4];
#pragma unroll
            for (int ft = 0; ft < 8; ft++) {
                short8 bf = *(const short8*)&wroot[((p * 8 + ft) * 64 + lane) * 8];
                acc[ft] = __builtin_amdgcn_mfma_f32_16x16x32_bf16(af, bf, acc[ft], 0, 0, 0);
            }
        }
        __syncthreads();
    }

    // epilogue: acc (C layout: row=quad*4+reg, col=ft*16+l15) -> fp32 LDS (waves 0-3)
    if (wave < 4) {
#pragma unroll
        for (int ft = 0; ft < 8; ft++)
#pragma unroll
            for (int rg = 0; rg < 4; rg++)
                SLF[(wave * 16 + quad * 4 + rg) * PADF + ft * 16 + l15] = acc[ft][rg];
    }
    __syncthreads();

    float2 bia = *(const float2*)&bias[2 * lane];
    float2 gam = *(const float2*)&gamma[2 * lane];
    float2 bet = *(const float2*)&beta[2 * lane];
    int sl = lane >> 4, sw = lane & 15;              // slice / within-slice for h dword

    for (int i = 0; i < 8; i++) {
        int row = wave * 8 + i;
        int g = n0 + row;
        if (g >= NN) continue;                       // wave-uniform
        float v0 = SLF[row * PADF + 2 * lane] + bia.x;
        float v1 = SLF[row * PADF + 2 * lane + 1] + bia.y;
        float s = v0 + v1;
#pragma unroll
        for (int off = 32; off > 0; off >>= 1) s += __shfl_xor(s, off, 64);
        float mu = s * (1.0f / ND);
        float e0 = v0 - mu, e1 = v1 - mu;
        float vs = e0 * e0 + e1 * e1;
#pragma unroll
        for (int off = 32; off > 0; off >>= 1) vs += __shfl_xor(vs, off, 64);
        float rr = rsqrtf(vs * (1.0f / ND) + LN_EPS);
        float o0 = fmaxf(e0 * rr * gam.x + bet.x, 0.0f);
        float o1 = fmaxf(e1 * rr * gam.y + bet.y, 0.0f);
        if (add_res) {
            unsigned u = hsl[((size_t)sl * NN + g) * 16 + sw];
            o0 += bflo(u);
            o1 += bfhi(u);
        }
        if (last) {
            *(float2*)&out_f[(size_t)g * ND + 2 * lane] = make_float2(o0, o1);
        } else {
            out_h[((size_t)sl * NN + g) * 16 + sw] = pack2(o0, o1);
        }
    }
}

extern "C" void kernel_launch(void* const* d_in, const int* in_sizes, int n_in,
                              void* d_out, int out_size, void* d_ws, size_t ws_size,
                              hipStream_t stream) {
    const int*   x      = (const int*)d_in[0];
    const int*   ei     = (const int*)d_in[1];
    const int*   et     = (const int*)d_in[2];
    const float* emb    = (const float*)d_in[3];
    const float* w_rel  = (const float*)d_in[4];
    const float* w_root = (const float*)d_in[5];
    const float* bias   = (const float*)d_in[6];
    const float* gamma  = (const float*)d_in[7];
    const float* beta   = (const float*)d_in[8];
    float* out = (float*)d_out;

    char* ws = (char*)d_ws;
    unsigned* h_a      = (unsigned*)(ws);                    // 12.8 MB (bf16x2, slice-major)
    unsigned* h_b      = (unsigned*)(ws + 12800000);         // 12.8 MB
    int*      cnt      = (int*)     (ws + 25600000);         // 1.6 MB
    float*    inv      = (float*)   (ws + 27200000);         // 1.6 MB
    int*      rowstart = (int*)     (ws + 28800000);         // 1.6 MB + 4
    int*      bsum     = (int*)     (ws + 30400064);
    int*      boff     = (int*)     (ws + 30402048);
    int*      adj      = (int*)     (ws + 30404096);         // 6.4 MB
    unsigned short* wb = (unsigned short*)(ws + 36804096);   // 884736 B

    const int* src = ei;
    const int* dst = ei + NE;

    hipMemsetAsync(cnt, 0, RN * sizeof(int), stream);
    k_gather<<<(NN * 64 + 255) / 256, 256, 0, stream>>>(x, emb, h_a);
    k_wprep<<<(27 * 16384 + 255) / 256, 256, 0, stream>>>(w_rel, w_root, wb);
    k_count<<<(NE + 255) / 256, 256, 0, stream>>>(dst, et, cnt);
    k_inv<<<(RN + 255) / 256, 256, 0, stream>>>(cnt, inv);
    k_scan1<<<NB, 256, 0, stream>>>(cnt, rowstart, bsum);
    k_scan2<<<1, 256, 0, stream>>>(bsum, boff);
    k_scan3<<<(RN + 255) / 256, 256, 0, stream>>>(rowstart, boff);
    k_fill<<<(NE + 255) / 256, 256, 0, stream>>>(src, dst, et, rowstart, cnt, adj);

    unsigned* h_cur = h_a;
    unsigned* h_nxt = h_b;
    for (int l = 0; l < NL; l++) {
        k_layer<<<(NN + 63) / 64, 512, 0, stream>>>(
            h_cur, adj, rowstart, inv,
            wb + (size_t)l * 8 * 16384, wb + (size_t)(24 + l) * 16384,
            bias + l * ND, gamma + l * ND, beta + l * ND,
            out, h_nxt, l > 0, l == NL - 1);
        unsigned* t = h_cur; h_cur = h_nxt; h_nxt = t;
    }
}